// Round 8
// baseline (328.858 us; speedup 1.0000x reference)
//
#include <hip/hip_runtime.h>

#define NE 40943
#define NR 18
#define ED 200
#define KWC 9
#define OC 32
#define WOUT 192
#define KOC 288      // KW*OC
#define KH 224       // padded K (ED 200 -> 224) for gemm2
#define CONV_BLOCKS ((NE * (KH / 4) + 287) / 288)  // 7962 (288-thread blocks)

typedef unsigned short u16;
typedef unsigned int u32;
typedef __bf16 bf16x8 __attribute__((ext_vector_type(8)));
typedef float f32x4 __attribute__((ext_vector_type(4)));
typedef u16 u16x8 __attribute__((ext_vector_type(8)));
typedef u16 u16x4 __attribute__((ext_vector_type(4)));

__device__ __forceinline__ u16 f2bf(float f) {
  u32 u = __builtin_bit_cast(u32, f);
  u32 r = (u + 0x7fffu + ((u >> 16) & 1u)) >> 16;
  return (u16)r;
}

// 16B global -> LDS direct DMA (wave-uniform LDS base + lane*16 layout)
__device__ __forceinline__ void gl_lds16(const u16* g, u16* l) {
  __builtin_amdgcn_global_load_lds(
      (const __attribute__((address_space(1))) u32*)g,
      (__attribute__((address_space(3))) u32*)l, 16, 0, 0);
}

// Fused (3 independent parts; prep_k folded in as an LDS phase — removes the
// 18-block serialized prep_k launch from the critical path; R2's regression was
// the o-split's 2x W2 traffic, NOT this fusion):
//   blocks [0,200):  phase1: krt[col][r] = b1 + sum_d R[r][d]*W1[d][col] (LDS)
//                    phase2: C[r][p][d] = sum_{j,o} krt * W2
//   blocks [200, 200+CONV_BLOCKS): Eb[n][c] = bf16(E[n][c])
__global__ __launch_bounds__(288) void build_c_conv_kernel(const float* __restrict__ R,
                                                           const float* __restrict__ W1,
                                                           const float* __restrict__ b1,
                                                           const float* __restrict__ W2,
                                                           float* __restrict__ C,
                                                           const float* __restrict__ E,
                                                           u16* __restrict__ Eb) {
  __shared__ float krt[KOC * NR];  // 20736 B
  if (blockIdx.x < ED) {
    const int t = threadIdx.x;  // 0..287
    // ---- phase 1: all 288 threads, one output column each
    {
      float acc[NR];
#pragma unroll
      for (int r = 0; r < NR; ++r) acc[r] = 0.f;
      for (int d = 0; d < ED; ++d) {
        float w1v = W1[d * KOC + t];  // coalesced across t
#pragma unroll
        for (int r = 0; r < NR; ++r) acc[r] += R[r * ED + d] * w1v;  // R uniform -> s_load
      }
      float b1v = b1[t];
#pragma unroll
      for (int r = 0; r < NR; ++r) krt[t * NR + r] = acc[r] + b1v;
    }
    __syncthreads();
    // ---- phase 2: threads 0..199 (one output d each), single o-pass (NO o-split)
    const int p = blockIdx.x;  // 0..199
    const int d = t;
    const int jlo = p > (WOUT - 1) ? p - (WOUT - 1) : 0;
    const int jhi = p < (KWC - 1) ? p : (KWC - 1);
    if (d < ED) {
      float acc[NR];
#pragma unroll
      for (int r = 0; r < NR; ++r) acc[r] = 0.f;
      for (int j = jlo; j <= jhi; ++j) {
        int w = p - j;
        const float* w2base = W2 + (size_t)w * ED + d;  // += o*192*200
        const float* kb = krt + (j * OC) * NR;          // LDS, wave-uniform -> broadcast
#pragma unroll
        for (int o = 0; o < OC; ++o) {
          float w2v = w2base[(size_t)o * WOUT * ED];
#pragma unroll
          for (int r = 0; r < NR; ++r) acc[r] += kb[o * NR + r] * w2v;
        }
      }
#pragma unroll
      for (int r = 0; r < NR; ++r) C[((size_t)r * ED + p) * ED + d] = acc[r];
    }
  } else {
    int idx = (blockIdx.x - ED) * 288 + threadIdx.x;
    const int total = NE * (KH / 4);
    if (idx >= total) return;
    int row = idx / (KH / 4);
    int c4 = (idx % (KH / 4)) * 4;
    u16x4 st = {0, 0, 0, 0};
    if (c4 < ED) {  // c4 in {0..196} fully valid; {200..220} zero — never straddles
      f32x4 v = *(const f32x4*)(E + (size_t)row * ED + c4);
      st[0] = f2bf(v[0]); st[1] = f2bf(v[1]); st[2] = f2bf(v[2]); st[3] = f2bf(v[3]);
    }
    *(u16x4*)(Eb + (size_t)row * KH + c4) = st;
  }
}

// Hb[b][d] = bf16(relu(sum_p E[e1_idx[b]][p] * C[r_idx[b]][p][d] + b2[d])), pad d in [200,224) = 0
// 4 independent partial chains break the 200-deep serial FMA dependency (ILP x4);
// reassociation noise << 2e-3 tolerance.
__global__ __launch_bounds__(256) void h_kernel(const int* __restrict__ e1_idx,
                                                const int* __restrict__ r_idx,
                                                const float* __restrict__ E,
                                                const float* __restrict__ C,
                                                const float* __restrict__ b2,
                                                u16* __restrict__ Hb) {
  __shared__ float e1s[ED];
  int b = blockIdx.x;
  int t = threadIdx.x;
  if (t < ED) e1s[t] = E[(size_t)e1_idx[b] * ED + t];
  __syncthreads();
  int r = r_idx[b];
  const float* Cr = C + (size_t)r * ED * ED;
  if (t < KH) {
    float acc = 0.f;
    if (t < ED) {
      float a0 = 0.f, a1 = 0.f, a2 = 0.f, a3 = 0.f;
#pragma unroll 4
      for (int p = 0; p < ED; p += 4) {
        a0 += e1s[p + 0] * Cr[(size_t)(p + 0) * ED + t];
        a1 += e1s[p + 1] * Cr[(size_t)(p + 1) * ED + t];
        a2 += e1s[p + 2] * Cr[(size_t)(p + 2) * ED + t];
        a3 += e1s[p + 3] * Cr[(size_t)(p + 3) * ED + t];
      }
      acc = ((a0 + a1) + (a2 + a3)) + b2[t];
      acc = acc > 0.f ? acc : 0.f;
    }
    Hb[(size_t)b * KH + t] = (t < ED) ? f2bf(acc) : (u16)0;
  }
}

// out[b][n] = sum_d Hb[b][d]*Eb[n][d] + bias[n]   (f32 out)
// T3+T4 counted-vmcnt pipeline (R5-exact K-loop, measured best): triple-buffered
// LDS, prefetch depth 3, raw s_barrier + counted vmcnt(8/4/0). Plain stores
// (nontemporal caused 2x TCC write amplification in R6 — never again); store
// order (mi,i,ni): temporally-adjacent same-row segments for write-combining.
__global__ __launch_bounds__(256) void gemm2_kernel(
    const u16* __restrict__ Hb,  // [1024][224]
    const u16* __restrict__ Eb,  // [40943][224]
    const float* __restrict__ bias,
    float* __restrict__ out) {
  __shared__ __align__(16) u16 lA[3][128 * 32];
  __shared__ __align__(16) u16 lB[3][128 * 32];
  const int t = threadIdx.x;
  const int wave = t >> 6, lane = t & 63;

  // XCD-bijective swizzle: grid = 2560 = 8 XCDs x 320; XCD x owns n-panels
  // [x*40, x*40+40) for ALL 8 m-tiles -> 2.3MB Eb resident per XCD L2.
  int id = blockIdx.x;
  int xcd = id & 7;
  int q = id >> 3;            // 0..319
  int bx = xcd * 40 + q % 40; // 0..319
  int by = q / 40;            // 0..7
  const int m0 = by * 128;
  const int n0 = bx * 128;
  const int wm = (wave >> 1) * 64, wn = (wave & 1) * 64;
  const int lr = lane & 15, lq = lane >> 4;
  // read-side swizzled k-chunk offset (u16 units), involution of the store side
  const int csw = (lq ^ ((lr >> 1) & 3)) * 8;

  // Staging: per tile each matrix = 128 rows x 64B = 512 x 16B chunks.
  // chunk = wave*128 + s*64 + lane -> LDS linear (base + lane*16, wave-uniform base).
  int aoff[2], boff[2], loff[2];
#pragma unroll
  for (int s = 0; s < 2; ++s) {
    int chunk = wave * 128 + s * 64 + lane;
    int r = chunk >> 2, cc = chunk & 3;
    int ccs = cc ^ ((r >> 1) & 3);     // source k-chunk stored at LDS chunk cc
    loff[s] = chunk * 8;               // u16 units
    aoff[s] = (m0 + r) * KH + ccs * 8;
    int gr = n0 + r;
    if (gr > NE - 1) gr = NE - 1;      // clamp: garbage-free, cols >= NE never stored
    boff[s] = gr * KH + ccs * 8;
  }

  f32x4 zero = {0.f, 0.f, 0.f, 0.f};
  f32x4 acc[4][4];
#pragma unroll
  for (int i = 0; i < 4; ++i)
#pragma unroll
    for (int j = 0; j < 4; ++j) acc[i][j] = zero;

// stage tile kt (4 vmem ops/thread) into buffer c
#define GSTAGE(kt, c)                                      \
  do {                                                     \
    gl_lds16(Hb + aoff[0] + (kt) * 32, &lA[c][loff[0]]);   \
    gl_lds16(Eb + boff[0] + (kt) * 32, &lB[c][loff[0]]);   \
    gl_lds16(Hb + aoff[1] + (kt) * 32, &lA[c][loff[1]]);   \
    gl_lds16(Eb + boff[1] + (kt) * 32, &lB[c][loff[1]]);   \
  } while (0)

// counted wait for next tile's 4 loads + barrier; sched_barrier pins (rule #18)
#define WAIT_SB(n)                                         \
  do {                                                     \
    asm volatile("s_waitcnt vmcnt(" #n ")" ::: "memory");  \
    __builtin_amdgcn_sched_barrier(0);                     \
    __builtin_amdgcn_s_barrier();                          \
    __builtin_amdgcn_sched_barrier(0);                     \
  } while (0)

// one K-step: ds_read frags from buf[cur]; lgkm-drain (ds only); barrier
// (buf[cur] now overwritable); optionally stage tile kt+3 into buf[cur]; MFMA.
#define KITER(kt, cur, dostage)                                                   \
  do {                                                                            \
    bf16x8 af[4], bfv[4];                                                         \
    _Pragma("unroll") for (int mi = 0; mi < 4; ++mi)                              \
        af[mi] = *(const bf16x8*)(&lA[cur][(wm + mi * 16 + lr) * 32 + csw]);      \
    _Pragma("unroll") for (int ni = 0; ni < 4; ++ni)                              \
        bfv[ni] = *(const bf16x8*)(&lB[cur][(wn + ni * 16 + lr) * 32 + csw]);     \
    asm volatile("s_waitcnt lgkmcnt(0)" ::: "memory");                            \
    __builtin_amdgcn_sched_barrier(0);                                            \
    __builtin_amdgcn_s_barrier();                                                 \
    __builtin_amdgcn_sched_barrier(0);                                            \
    if (dostage) GSTAGE((kt) + 3, cur);                                           \
    __builtin_amdgcn_s_setprio(1);                                                \
    _Pragma("unroll") for (int mi = 0; mi < 4; ++mi)                              \
        _Pragma("unroll") for (int ni = 0; ni < 4; ++ni)                          \
            acc[mi][ni] = __builtin_amdgcn_mfma_f32_16x16x32_bf16(                \
                af[mi], bfv[ni], acc[mi][ni], 0, 0, 0);                           \
    __builtin_amdgcn_s_setprio(0);                                                \
  } while (0)

  // prologue: prefetch tiles 0,1,2 (12 vmem in flight); tile0 ready at vmcnt<=8
  GSTAGE(0, 0);
  GSTAGE(1, 1);
  GSTAGE(2, 2);
  WAIT_SB(8);

  // 7 K-tiles, fully unrolled; vmcnt counts: steady 8 (2 future tiles in flight
  // after this one), tail 4 then 0.
  KITER(0, 0, 1); WAIT_SB(8);
  KITER(1, 1, 1); WAIT_SB(8);
  KITER(2, 2, 1); WAIT_SB(8);
  KITER(3, 0, 1); WAIT_SB(8);
  KITER(4, 1, 0); WAIT_SB(4);
  KITER(5, 2, 0); WAIT_SB(0);
  KITER(6, 0, 0);

#undef KITER
#undef WAIT_SB
#undef GSTAGE

  // Epilogue: plain stores; order (mi, i, ni) -> consecutive stores hit the SAME
  // output row at cols +0/+16/+32/+48 (adjacent-in-time for TCC write-combining).
  float bv[4];
  bool cok[4];
  int cols[4];
#pragma unroll
  for (int ni = 0; ni < 4; ++ni) {
    cols[ni] = n0 + wn + ni * 16 + lr;
    cok[ni] = cols[ni] < NE;
    bv[ni] = cok[ni] ? bias[cols[ni]] : 0.f;
  }
#pragma unroll
  for (int mi = 0; mi < 4; ++mi) {
    int row = m0 + wm + mi * 16 + lq * 4;
#pragma unroll
    for (int i = 0; i < 4; ++i) {
      size_t rb = (size_t)(row + i) * NE;
#pragma unroll
      for (int ni = 0; ni < 4; ++ni) {
        if (cok[ni]) out[rb + cols[ni]] = acc[mi][ni][i] + bv[ni];
      }
    }
  }
}

extern "C" void kernel_launch(void* const* d_in, const int* in_sizes, int n_in,
                              void* d_out, int out_size, void* d_ws, size_t ws_size,
                              hipStream_t stream) {
  const int* e1_idx = (const int*)d_in[0];
  const int* r_idx = (const int*)d_in[1];
  const float* W1 = (const float*)d_in[2];
  const float* b1 = (const float*)d_in[3];
  const float* W2 = (const float*)d_in[4];
  const float* b2 = (const float*)d_in[5];
  const float* bias_logits = (const float*)d_in[6];
  const float* E = (const float*)d_in[7];
  const float* R = (const float*)d_in[8];
  float* out = (float*)d_out;

  char* ws = (char*)d_ws;
  float* C = (float*)(ws + 32768);                  // 18*200*200*4 = 2,880,000
  u16* Hb = (u16*)(ws + 32768 + 2880000);           // 1024*224*2 = 458,752
  u16* Eb = (u16*)(ws + 32768 + 2880000 + 458752);  // 40943*224*2 = 18,342,464

  build_c_conv_kernel<<<dim3(ED + CONV_BLOCKS), dim3(288), 0, stream>>>(R, W1, b1, W2, C, E, Eb);
  h_kernel<<<dim3(1024), dim3(256), 0, stream>>>(e1_idx, r_idx, E, C, b2, Hb);
  gemm2_kernel<<<dim3(320 * 8), dim3(256), 0, stream>>>(Hb, Eb, bias_logits, out);
}

// Round 9
// 291.140 us; speedup vs baseline: 1.1296x; 1.1296x over previous
//
#include <hip/hip_runtime.h>

#define NE 40943
#define NR 18
#define ED 200
#define KWC 9
#define OC 32
#define WOUT 192
#define KOC 288      // KW*OC
#define KH 224       // padded K (ED 200 -> 224) for gemm2
#define CONV_BLOCKS ((NE * (KH / 4) + 255) / 256)  // 8957

typedef unsigned short u16;
typedef unsigned int u32;
typedef __bf16 bf16x8 __attribute__((ext_vector_type(8)));
typedef float f32x4 __attribute__((ext_vector_type(4)));
typedef u16 u16x8 __attribute__((ext_vector_type(8)));
typedef u16 u16x4 __attribute__((ext_vector_type(4)));

__device__ __forceinline__ u16 f2bf(float f) {
  u32 u = __builtin_bit_cast(u32, f);
  u32 r = (u + 0x7fffu + ((u >> 16) & 1u)) >> 16;
  return (u16)r;
}

// 16B global -> LDS direct DMA (wave-uniform LDS base + lane*16 layout)
__device__ __forceinline__ void gl_lds16(const u16* g, u16* l) {
  __builtin_amdgcn_global_load_lds(
      (const __attribute__((address_space(1))) u32*)g,
      (__attribute__((address_space(3))) u32*)l, 16, 0, 0);
}

// KrT[j*32+o][rel] = sum_d R[rel][d] * W1[d][j*32+o] + b1[j*32+o]   (288 x 18, f32)
__global__ void prep_k_kernel(const float* __restrict__ R,
                              const float* __restrict__ W1,
                              const float* __restrict__ b1,
                              float* __restrict__ KrT) {
  int rel = blockIdx.x;
  int j = threadIdx.x;  // 0..287
  float acc = b1[j];
  const float* rrow = R + rel * ED;
  for (int d = 0; d < ED; ++d) acc += rrow[d] * W1[d * KOC + j];
  KrT[j * NR + rel] = acc;
}

// Fused (independent halves, saves one launch + overlaps traffic):
//   blocks [0,200):        C[r][p][d] = sum KrT * W2   (build_c, critical path, dispatches first)
//   blocks [200,200+8957): Eb[n][c] = bf16(E[n][c])    (conv_e)
__global__ __launch_bounds__(256) void build_c_conv_kernel(const float* __restrict__ KrT,
                                                           const float* __restrict__ W2,
                                                           float* __restrict__ C,
                                                           const float* __restrict__ E,
                                                           u16* __restrict__ Eb) {
  if (blockIdx.x < ED) {
    int p = blockIdx.x;   // 0..199
    int d = threadIdx.x;  // active < 200
    int jlo = p > (WOUT - 1) ? p - (WOUT - 1) : 0;
    int jhi = p < (KWC - 1) ? p : (KWC - 1);
    if (d < ED) {
      float acc[NR];
#pragma unroll
      for (int r = 0; r < NR; ++r) acc[r] = 0.f;
      for (int j = jlo; j <= jhi; ++j) {
        int w = p - j;
        const float* w2base = W2 + (size_t)w * ED + d;  // += o*192*200
        const float* kb = KrT + (j * OC) * NR;          // block-uniform -> s_load
#pragma unroll
        for (int o = 0; o < OC; ++o) {
          float w2v = w2base[(size_t)o * WOUT * ED];
#pragma unroll
          for (int r = 0; r < NR; ++r) acc[r] += kb[o * NR + r] * w2v;
        }
      }
#pragma unroll
      for (int r = 0; r < NR; ++r) C[((size_t)r * ED + p) * ED + d] = acc[r];
    }
  } else {
    int idx = (blockIdx.x - ED) * 256 + threadIdx.x;
    const int total = NE * (KH / 4);
    if (idx >= total) return;
    int row = idx / (KH / 4);
    int c4 = (idx % (KH / 4)) * 4;
    u16x4 st = {0, 0, 0, 0};
    if (c4 < ED) {  // c4 in {0..196} fully valid; {200..220} zero — never straddles
      f32x4 v = *(const f32x4*)(E + (size_t)row * ED + c4);
      st[0] = f2bf(v[0]); st[1] = f2bf(v[1]); st[2] = f2bf(v[2]); st[3] = f2bf(v[3]);
    }
    *(u16x4*)(Eb + (size_t)row * KH + c4) = st;
  }
}

// Hb[b][d] = bf16(relu(sum_p E[e1_idx[b]][p] * C[r_idx[b]][p][d] + b2[d])), pad d in [200,224) = 0
__global__ __launch_bounds__(256) void h_kernel(const int* __restrict__ e1_idx,
                                                const int* __restrict__ r_idx,
                                                const float* __restrict__ E,
                                                const float* __restrict__ C,
                                                const float* __restrict__ b2,
                                                u16* __restrict__ Hb) {
  __shared__ float e1s[ED];
  int b = blockIdx.x;
  int t = threadIdx.x;
  if (t < ED) e1s[t] = E[(size_t)e1_idx[b] * ED + t];
  __syncthreads();
  int r = r_idx[b];
  const float* Cr = C + (size_t)r * ED * ED;
  if (t < KH) {
    float acc = 0.f;
    if (t < ED) {
#pragma unroll 8
      for (int p = 0; p < ED; ++p) acc += e1s[p] * Cr[(size_t)p * ED + t];
      acc += b2[t];
      acc = acc > 0.f ? acc : 0.f;
    }
    Hb[(size_t)b * KH + t] = (t < ED) ? f2bf(acc) : (u16)0;
  }
}

// out[b][n] = sum_d Hb[b][d]*Eb[n][d] + bias[n]   (f32 out)
// T3+T4 counted-vmcnt pipeline (R5-exact, measured best): triple-buffered LDS,
// prefetch depth 3, raw s_barrier + counted vmcnt(8/4/0) — prefetches stay in
// flight ACROSS barriers. Plain stores (R6's nontemporal stores caused 2x write
// amplification at TCC: WRITE_SIZE 343MB vs 167.7MB output — never again).
__global__ __launch_bounds__(256) void gemm2_kernel(
    const u16* __restrict__ Hb,  // [1024][224]
    const u16* __restrict__ Eb,  // [40943][224]
    const float* __restrict__ bias,
    float* __restrict__ out) {
  __shared__ __align__(16) u16 lA[3][128 * 32];
  __shared__ __align__(16) u16 lB[3][128 * 32];
  const int t = threadIdx.x;
  const int wave = t >> 6, lane = t & 63;

  // XCD-bijective swizzle: grid = 2560 = 8 XCDs x 320; XCD x owns n-panels
  // [x*40, x*40+40) for ALL 8 m-tiles -> 2.3MB Eb resident per XCD L2.
  int id = blockIdx.x;
  int xcd = id & 7;
  int q = id >> 3;            // 0..319
  int bx = xcd * 40 + q % 40; // 0..319
  int by = q / 40;            // 0..7
  const int m0 = by * 128;
  const int n0 = bx * 128;
  const int wm = (wave >> 1) * 64, wn = (wave & 1) * 64;
  const int lr = lane & 15, lq = lane >> 4;
  // read-side swizzled k-chunk offset (u16 units), involution of the store side
  const int csw = (lq ^ ((lr >> 1) & 3)) * 8;

  // Staging: per tile each matrix = 128 rows x 64B = 512 x 16B chunks.
  // chunk = wave*128 + s*64 + lane -> LDS linear (base + lane*16, wave-uniform base).
  int aoff[2], boff[2], loff[2];
#pragma unroll
  for (int s = 0; s < 2; ++s) {
    int chunk = wave * 128 + s * 64 + lane;
    int r = chunk >> 2, cc = chunk & 3;
    int ccs = cc ^ ((r >> 1) & 3);     // source k-chunk stored at LDS chunk cc
    loff[s] = chunk * 8;               // u16 units
    aoff[s] = (m0 + r) * KH + ccs * 8;
    int gr = n0 + r;
    if (gr > NE - 1) gr = NE - 1;      // clamp: garbage-free, cols >= NE never stored
    boff[s] = gr * KH + ccs * 8;
  }

  f32x4 zero = {0.f, 0.f, 0.f, 0.f};
  f32x4 acc[4][4];
#pragma unroll
  for (int i = 0; i < 4; ++i)
#pragma unroll
    for (int j = 0; j < 4; ++j) acc[i][j] = zero;

// stage tile kt (4 vmem ops/thread) into buffer c
#define GSTAGE(kt, c)                                      \
  do {                                                     \
    gl_lds16(Hb + aoff[0] + (kt) * 32, &lA[c][loff[0]]);   \
    gl_lds16(Eb + boff[0] + (kt) * 32, &lB[c][loff[0]]);   \
    gl_lds16(Hb + aoff[1] + (kt) * 32, &lA[c][loff[1]]);   \
    gl_lds16(Eb + boff[1] + (kt) * 32, &lB[c][loff[1]]);   \
  } while (0)

// counted wait for next tile's 4 loads + barrier; sched_barrier pins (rule #18)
#define WAIT_SB(n)                                         \
  do {                                                     \
    asm volatile("s_waitcnt vmcnt(" #n ")" ::: "memory");  \
    __builtin_amdgcn_sched_barrier(0);                     \
    __builtin_amdgcn_s_barrier();                          \
    __builtin_amdgcn_sched_barrier(0);                     \
  } while (0)

// one K-step: ds_read frags from buf[cur]; lgkm-drain (ds only); barrier
// (buf[cur] now overwritable); optionally stage tile kt+3 into buf[cur]; MFMA.
#define KITER(kt, cur, dostage)                                                   \
  do {                                                                            \
    bf16x8 af[4], bfv[4];                                                         \
    _Pragma("unroll") for (int mi = 0; mi < 4; ++mi)                              \
        af[mi] = *(const bf16x8*)(&lA[cur][(wm + mi * 16 + lr) * 32 + csw]);      \
    _Pragma("unroll") for (int ni = 0; ni < 4; ++ni)                              \
        bfv[ni] = *(const bf16x8*)(&lB[cur][(wn + ni * 16 + lr) * 32 + csw]);     \
    asm volatile("s_waitcnt lgkmcnt(0)" ::: "memory");                            \
    __builtin_amdgcn_sched_barrier(0);                                            \
    __builtin_amdgcn_s_barrier();                                                 \
    __builtin_amdgcn_sched_barrier(0);                                            \
    if (dostage) GSTAGE((kt) + 3, cur);                                           \
    __builtin_amdgcn_s_setprio(1);                                                \
    _Pragma("unroll") for (int mi = 0; mi < 4; ++mi)                              \
        _Pragma("unroll") for (int ni = 0; ni < 4; ++ni)                          \
            acc[mi][ni] = __builtin_amdgcn_mfma_f32_16x16x32_bf16(                \
                af[mi], bfv[ni], acc[mi][ni], 0, 0, 0);                           \
    __builtin_amdgcn_s_setprio(0);                                                \
  } while (0)

  // prologue: prefetch tiles 0,1,2 (12 vmem in flight); tile0 ready at vmcnt<=8
  GSTAGE(0, 0);
  GSTAGE(1, 1);
  GSTAGE(2, 2);
  WAIT_SB(8);

  // 7 K-tiles, fully unrolled; vmcnt counts: steady 8 (2 future tiles in flight
  // after this one), tail 4 then 0.
  KITER(0, 0, 1); WAIT_SB(8);
  KITER(1, 1, 1); WAIT_SB(8);
  KITER(2, 2, 1); WAIT_SB(8);
  KITER(3, 0, 1); WAIT_SB(8);
  KITER(4, 1, 0); WAIT_SB(4);
  KITER(5, 2, 0); WAIT_SB(0);
  KITER(6, 0, 0);

#undef KITER
#undef WAIT_SB
#undef GSTAGE

#pragma unroll
  for (int mi = 0; mi < 4; ++mi) {
    int row = m0 + wm + mi * 16 + lq * 4;
#pragma unroll
    for (int ni = 0; ni < 4; ++ni) {
      int col = n0 + wn + ni * 16 + lr;
      if (col < NE) {
        float bv = bias[col];
#pragma unroll
        for (int i = 0; i < 4; ++i)
          out[(size_t)(row + i) * NE + col] = acc[mi][ni][i] + bv;
      }
    }
  }
}

extern "C" void kernel_launch(void* const* d_in, const int* in_sizes, int n_in,
                              void* d_out, int out_size, void* d_ws, size_t ws_size,
                              hipStream_t stream) {
  const int* e1_idx = (const int*)d_in[0];
  const int* r_idx = (const int*)d_in[1];
  const float* W1 = (const float*)d_in[2];
  const float* b1 = (const float*)d_in[3];
  const float* W2 = (const float*)d_in[4];
  const float* b2 = (const float*)d_in[5];
  const float* bias_logits = (const float*)d_in[6];
  const float* E = (const float*)d_in[7];
  const float* R = (const float*)d_in[8];
  float* out = (float*)d_out;

  char* ws = (char*)d_ws;
  float* KrT = (float*)ws;                          // 288*18*4 = 20,736
  float* C = (float*)(ws + 32768);                  // 18*200*200*4 = 2,880,000
  u16* Hb = (u16*)(ws + 32768 + 2880000);           // 1024*224*2 = 458,752
  u16* Eb = (u16*)(ws + 32768 + 2880000 + 458752);  // 40943*224*2 = 18,342,464

  prep_k_kernel<<<dim3(NR), dim3(KOC), 0, stream>>>(R, W1, b1, KrT);
  build_c_conv_kernel<<<dim3(ED + CONV_BLOCKS), dim3(256), 0, stream>>>(KrT, W2, C, E, Eb);
  h_kernel<<<dim3(1024), dim3(256), 0, stream>>>(e1_idx, r_idx, E, C, b2, Hb);
  gemm2_kernel<<<dim3(320 * 8), dim3(256), 0, stream>>>(Hb, Eb, bias_logits, out);
}

// Round 11
// 290.226 us; speedup vs baseline: 1.1331x; 1.0032x over previous
//
#include <hip/hip_runtime.h>

#define NE 40943
#define NR 18
#define ED 200
#define KWC 9
#define OC 32
#define WOUT 192
#define KOC 288      // KW*OC
#define KH 224       // padded K (ED 200 -> 224) for gemm2
#define CONV_BLOCKS ((NE * (KH / 4) + 255) / 256)  // 8957

typedef unsigned short u16;
typedef unsigned int u32;
typedef __bf16 bf16x8 __attribute__((ext_vector_type(8)));
typedef float f32x4 __attribute__((ext_vector_type(4)));
typedef u16 u16x8 __attribute__((ext_vector_type(8)));
typedef u16 u16x4 __attribute__((ext_vector_type(4)));

__device__ __forceinline__ u16 f2bf(float f) {
  u32 u = __builtin_bit_cast(u32, f);
  u32 r = (u + 0x7fffu + ((u >> 16) & 1u)) >> 16;
  return (u16)r;
}

// 16B global -> LDS direct DMA (wave-uniform LDS base + lane*16 layout)
__device__ __forceinline__ void gl_lds16(const u16* g, u16* l) {
  __builtin_amdgcn_global_load_lds(
      (const __attribute__((address_space(1))) u32*)g,
      (__attribute__((address_space(3))) u32*)l, 16, 0, 0);
}

// KrT[j*32+o][rel] = sum_d R[rel][d] * W1[d][j*32+o] + b1[j*32+o]   (288 x 18, f32)
__global__ void prep_k_kernel(const float* __restrict__ R,
                              const float* __restrict__ W1,
                              const float* __restrict__ b1,
                              float* __restrict__ KrT) {
  int rel = blockIdx.x;
  int j = threadIdx.x;  // 0..287
  float acc = b1[j];
  const float* rrow = R + rel * ED;
  for (int d = 0; d < ED; ++d) acc += rrow[d] * W1[d * KOC + j];
  KrT[j * NR + rel] = acc;
}

// Fused (independent halves, saves one launch + overlaps traffic):
//   blocks [0,200):        C[r][p][d] = sum KrT * W2   (build_c, critical path, dispatches first)
//   blocks [200,200+8957): Eb[n][c] = bf16(E[n][c])    (conv_e)
__global__ __launch_bounds__(256) void build_c_conv_kernel(const float* __restrict__ KrT,
                                                           const float* __restrict__ W2,
                                                           float* __restrict__ C,
                                                           const float* __restrict__ E,
                                                           u16* __restrict__ Eb) {
  if (blockIdx.x < ED) {
    int p = blockIdx.x;   // 0..199
    int d = threadIdx.x;  // active < 200
    int jlo = p > (WOUT - 1) ? p - (WOUT - 1) : 0;
    int jhi = p < (KWC - 1) ? p : (KWC - 1);
    if (d < ED) {
      float acc[NR];
#pragma unroll
      for (int r = 0; r < NR; ++r) acc[r] = 0.f;
      for (int j = jlo; j <= jhi; ++j) {
        int w = p - j;
        const float* w2base = W2 + (size_t)w * ED + d;  // += o*192*200
        const float* kb = KrT + (j * OC) * NR;          // block-uniform -> s_load
#pragma unroll
        for (int o = 0; o < OC; ++o) {
          float w2v = w2base[(size_t)o * WOUT * ED];
#pragma unroll
          for (int r = 0; r < NR; ++r) acc[r] += kb[o * NR + r] * w2v;
        }
      }
#pragma unroll
      for (int r = 0; r < NR; ++r) C[((size_t)r * ED + p) * ED + d] = acc[r];
    }
  } else {
    int idx = (blockIdx.x - ED) * 256 + threadIdx.x;
    const int total = NE * (KH / 4);
    if (idx >= total) return;
    int row = idx / (KH / 4);
    int c4 = (idx % (KH / 4)) * 4;
    u16x4 st = {0, 0, 0, 0};
    if (c4 < ED) {  // c4 in {0..196} fully valid; {200..220} zero — never straddles
      f32x4 v = *(const f32x4*)(E + (size_t)row * ED + c4);
      st[0] = f2bf(v[0]); st[1] = f2bf(v[1]); st[2] = f2bf(v[2]); st[3] = f2bf(v[3]);
    }
    *(u16x4*)(Eb + (size_t)row * KH + c4) = st;
  }
}

// Hb[b][d] = bf16(relu(sum_p E[e1_idx[b]][p] * C[r_idx[b]][p][d] + b2[d])), pad d in [200,224) = 0
__global__ __launch_bounds__(256) void h_kernel(const int* __restrict__ e1_idx,
                                                const int* __restrict__ r_idx,
                                                const float* __restrict__ E,
                                                const float* __restrict__ C,
                                                const float* __restrict__ b2,
                                                u16* __restrict__ Hb) {
  __shared__ float e1s[ED];
  int b = blockIdx.x;
  int t = threadIdx.x;
  if (t < ED) e1s[t] = E[(size_t)e1_idx[b] * ED + t];
  __syncthreads();
  int r = r_idx[b];
  const float* Cr = C + (size_t)r * ED * ED;
  if (t < KH) {
    float acc = 0.f;
    if (t < ED) {
#pragma unroll 8
      for (int p = 0; p < ED; ++p) acc += e1s[p] * Cr[(size_t)p * ED + t];
      acc += b2[t];
      acc = acc > 0.f ? acc : 0.f;
    }
    Hb[(size_t)b * KH + t] = (t < ED) ? f2bf(acc) : (u16)0;
  }
}

// out[b][n] = sum_d Hb[b][d]*Eb[n][d] + bias[n]   (f32 out)
// T3+T4 counted-vmcnt pipeline, DEPTH-2 (single change under test vs R7/R9 best):
// 32KB LDS -> 4 blocks/CU (was 48KB/3) for cross-block epilogue/K-loop overlap.
// Same barrier structure; steady vmcnt(4), tail vmcnt(0). Plain stores
// (R6's nontemporal stores caused 2x TCC write amplification — never again).
__global__ __launch_bounds__(256) void gemm2_kernel(
    const u16* __restrict__ Hb,  // [1024][224]
    const u16* __restrict__ Eb,  // [40943][224]
    const float* __restrict__ bias,
    float* __restrict__ out) {
  __shared__ __align__(16) u16 lA[2][128 * 32];
  __shared__ __align__(16) u16 lB[2][128 * 32];
  const int t = threadIdx.x;
  const int wave = t >> 6, lane = t & 63;

  // XCD-bijective swizzle: grid = 2560 = 8 XCDs x 320; XCD x owns n-panels
  // [x*40, x*40+40) for ALL 8 m-tiles -> 2.3MB Eb resident per XCD L2.
  int id = blockIdx.x;
  int xcd = id & 7;
  int q = id >> 3;            // 0..319
  int bx = xcd * 40 + q % 40; // 0..319
  int by = q / 40;            // 0..7
  const int m0 = by * 128;
  const int n0 = bx * 128;
  const int wm = (wave >> 1) * 64, wn = (wave & 1) * 64;
  const int lr = lane & 15, lq = lane >> 4;
  // read-side swizzled k-chunk offset (u16 units), involution of the store side
  const int csw = (lq ^ ((lr >> 1) & 3)) * 8;

  // Staging: per tile each matrix = 128 rows x 64B = 512 x 16B chunks.
  // chunk = wave*128 + s*64 + lane -> LDS linear (base + lane*16, wave-uniform base).
  int aoff[2], boff[2], loff[2];
#pragma unroll
  for (int s = 0; s < 2; ++s) {
    int chunk = wave * 128 + s * 64 + lane;
    int r = chunk >> 2, cc = chunk & 3;
    int ccs = cc ^ ((r >> 1) & 3);     // source k-chunk stored at LDS chunk cc
    loff[s] = chunk * 8;               // u16 units
    aoff[s] = (m0 + r) * KH + ccs * 8;
    int gr = n0 + r;
    if (gr > NE - 1) gr = NE - 1;      // clamp: garbage-free, cols >= NE never stored
    boff[s] = gr * KH + ccs * 8;
  }

  f32x4 zero = {0.f, 0.f, 0.f, 0.f};
  f32x4 acc[4][4];
#pragma unroll
  for (int i = 0; i < 4; ++i)
#pragma unroll
    for (int j = 0; j < 4; ++j) acc[i][j] = zero;

// stage tile kt (4 vmem ops/thread) into buffer c
#define GSTAGE(kt, c)                                      \
  do {                                                     \
    gl_lds16(Hb + aoff[0] + (kt) * 32, &lA[c][loff[0]]);   \
    gl_lds16(Eb + boff[0] + (kt) * 32, &lB[c][loff[0]]);   \
    gl_lds16(Hb + aoff[1] + (kt) * 32, &lA[c][loff[1]]);   \
    gl_lds16(Eb + boff[1] + (kt) * 32, &lB[c][loff[1]]);   \
  } while (0)

// counted wait for next tile's 4 loads + barrier; sched_barrier pins (rule #18)
#define WAIT_SB(n)                                         \
  do {                                                     \
    asm volatile("s_waitcnt vmcnt(" #n ")" ::: "memory");  \
    __builtin_amdgcn_sched_barrier(0);                     \
    __builtin_amdgcn_s_barrier();                          \
    __builtin_amdgcn_sched_barrier(0);                     \
  } while (0)

// one K-step: ds_read frags from buf[cur]; lgkm-drain (ds only); barrier
// (buf[cur] now overwritable); optionally stage tile kt+2 into buf[cur]; MFMA.
#define KITER(kt, cur, dostage)                                                   \
  do {                                                                            \
    bf16x8 af[4], bfv[4];                                                         \
    _Pragma("unroll") for (int mi = 0; mi < 4; ++mi)                              \
        af[mi] = *(const bf16x8*)(&lA[cur][(wm + mi * 16 + lr) * 32 + csw]);      \
    _Pragma("unroll") for (int ni = 0; ni < 4; ++ni)                              \
        bfv[ni] = *(const bf16x8*)(&lB[cur][(wn + ni * 16 + lr) * 32 + csw]);     \
    asm volatile("s_waitcnt lgkmcnt(0)" ::: "memory");                            \
    __builtin_amdgcn_sched_barrier(0);                                            \
    __builtin_amdgcn_s_barrier();                                                 \
    __builtin_amdgcn_sched_barrier(0);                                            \
    if (dostage) GSTAGE((kt) + 2, cur);                                           \
    __builtin_amdgcn_s_setprio(1);                                                \
    _Pragma("unroll") for (int mi = 0; mi < 4; ++mi)                              \
        _Pragma("unroll") for (int ni = 0; ni < 4; ++ni)                          \
            acc[mi][ni] = __builtin_amdgcn_mfma_f32_16x16x32_bf16(                \
                af[mi], bfv[ni], acc[mi][ni], 0, 0, 0);                           \
    __builtin_amdgcn_s_setprio(0);                                                \
  } while (0)

  // prologue: prefetch tiles 0,1 (8 vmem in flight); tile0 ready at vmcnt<=4
  GSTAGE(0, 0);
  GSTAGE(1, 1);
  WAIT_SB(4);

  // 7 K-tiles, fully unrolled; depth-2: after KITER(kt) stages kt+2, in flight =
  // tiles kt+1, kt+2 (8 ops) -> wait vmcnt(4) for kt+1. Tail drains 0.
  KITER(0, 0, 1); WAIT_SB(4);
  KITER(1, 1, 1); WAIT_SB(4);
  KITER(2, 0, 1); WAIT_SB(4);
  KITER(3, 1, 1); WAIT_SB(4);
  KITER(4, 0, 1); WAIT_SB(4);
  KITER(5, 1, 0); WAIT_SB(0);
  KITER(6, 0, 0);

#undef KITER
#undef WAIT_SB
#undef GSTAGE

#pragma unroll
  for (int mi = 0; mi < 4; ++mi) {
    int row = m0 + wm + mi * 16 + lq * 4;
#pragma unroll
    for (int ni = 0; ni < 4; ++ni) {
      int col = n0 + wn + ni * 16 + lr;
      if (col < NE) {
        float bv = bias[col];
#pragma unroll
        for (int i = 0; i < 4; ++i)
          out[(size_t)(row + i) * NE + col] = acc[mi][ni][i] + bv;
      }
    }
  }
}

extern "C" void kernel_launch(void* const* d_in, const int* in_sizes, int n_in,
                              void* d_out, int out_size, void* d_ws, size_t ws_size,
                              hipStream_t stream) {
  const int* e1_idx = (const int*)d_in[0];
  const int* r_idx = (const int*)d_in[1];
  const float* W1 = (const float*)d_in[2];
  const float* b1 = (const float*)d_in[3];
  const float* W2 = (const float*)d_in[4];
  const float* b2 = (const float*)d_in[5];
  const float* bias_logits = (const float*)d_in[6];
  const float* E = (const float*)d_in[7];
  const float* R = (const float*)d_in[8];
  float* out = (float*)d_out;

  char* ws = (char*)d_ws;
  float* KrT = (float*)ws;                          // 288*18*4 = 20,736
  float* C = (float*)(ws + 32768);                  // 18*200*200*4 = 2,880,000
  u16* Hb = (u16*)(ws + 32768 + 2880000);           // 1024*224*2 = 458,752
  u16* Eb = (u16*)(ws + 32768 + 2880000 + 458752);  // 40943*224*2 = 18,342,464

  prep_k_kernel<<<dim3(NR), dim3(KOC), 0, stream>>>(R, W1, b1, KrT);
  build_c_conv_kernel<<<dim3(ED + CONV_BLOCKS), dim3(256), 0, stream>>>(KrT, W2, C, E, Eb);
  h_kernel<<<dim3(1024), dim3(256), 0, stream>>>(e1_idx, r_idx, E, C, b2, Hb);
  gemm2_kernel<<<dim3(320 * 8), dim3(256), 0, stream>>>(Hb, Eb, bias_logits, out);
}